// Round 1
// baseline (1364.142 us; speedup 1.0000x reference)
//
#include <hip/hip_runtime.h>

using u16 = unsigned short;
using u32 = unsigned int;
typedef __attribute__((ext_vector_type(8))) short short8;   // 8 bf16 (4 VGPRs) MFMA frag
typedef __attribute__((ext_vector_type(4))) float f32x4;
typedef __attribute__((ext_vector_type(4))) u16 us4;        // 8-byte bf16x4

#define MFMA16(a, b, c) __builtin_amdgcn_mfma_f32_16x16x32_bf16((a), (b), (c), 0, 0, 0)

__device__ __forceinline__ u16 f2bf(float f) {
  u32 u = __builtin_bit_cast(u32, f);
  u += 0x7fffu + ((u >> 16) & 1u);   // round-to-nearest-even
  return (u16)(u >> 16);
}

// ---------------- kernel 0: fp32 -> bf16 conversions ----------------
__global__ void cvt_kernel(const float* __restrict__ x, const float* __restrict__ wq,
                           const float* __restrict__ wp, u16* __restrict__ x_bf,
                           u16* __restrict__ wq_bf, u16* __restrict__ wp_bf) {
  const int NX = 6291456 / 4, NWQ = 442368 / 4, NWP = 147456 / 4;
  int stride = gridDim.x * blockDim.x;
  for (int i = blockIdx.x * blockDim.x + threadIdx.x; i < NX + NWQ + NWP; i += stride) {
    const f32x4* src; us4* dst; int j;
    if (i < NX)            { src = (const f32x4*)x;  dst = (us4*)x_bf;  j = i; }
    else if (i < NX + NWQ) { src = (const f32x4*)wq; dst = (us4*)wq_bf; j = i - NX; }
    else                   { src = (const f32x4*)wp; dst = (us4*)wp_bf; j = i - NX - NWQ; }
    f32x4 v = src[j];
    us4 o; o.x = f2bf(v[0]); o.y = f2bf(v[1]); o.z = f2bf(v[2]); o.w = f2bf(v[3]);
    dst[j] = o;
  }
}

// ---------------- kernel 1: QKV projection GEMM ----------------
// out cols j = s*384 + h*64 + d ; s=0:Q (scaled 1/8), s=1:K, s=2:V (stored transposed)
__global__ __launch_bounds__(256) void qkv_kernel(const u16* __restrict__ x_bf,
    const u16* __restrict__ wq_bf, u16* __restrict__ q_ws, u16* __restrict__ k_ws,
    u16* __restrict__ vt_ws) {
  int jt = blockIdx.x;                 // 0..17 (64-wide col tile; never straddles head)
  int mt = blockIdx.y;                 // 0..255 (64-wide row tile)
  int s = jt / 6, h = jt % 6;
  int w = threadIdx.x >> 6, lane = threadIdx.x & 63;
  int r = lane & 15, g = lane >> 4;
  int m0 = mt * 64 + w * 16;

  f32x4 acc[4];
  #pragma unroll
  for (int jj = 0; jj < 4; ++jj) acc[jj] = (f32x4){0.f, 0.f, 0.f, 0.f};

  const u16* xrow = x_bf + (size_t)(m0 + r) * 384 + g * 8;
  const u16* wrow = wq_bf + (size_t)(jt * 64 + r) * 384 + g * 8;
  #pragma unroll
  for (int ks = 0; ks < 12; ++ks) {
    short8 af = *(const short8*)(xrow + ks * 32);
    #pragma unroll
    for (int jj = 0; jj < 4; ++jj) {
      short8 bfr = *(const short8*)(wrow + (size_t)jj * 16 * 384 + ks * 32);
      acc[jj] = MFMA16(af, bfr, acc[jj]);
    }
  }
  int b = mt >> 5;                 // 2048/64 = 32 row-tiles per batch
  int n0 = (mt * 64) & 2047;
  int bh = b * 6 + h;
  if (s == 2) {
    // V transposed: vt[bh][d][n]; lane holds fixed d = jj*16+r, 4 consecutive n
    #pragma unroll
    for (int jj = 0; jj < 4; ++jj) {
      us4 o; o.x = f2bf(acc[jj][0]); o.y = f2bf(acc[jj][1]);
      o.z = f2bf(acc[jj][2]); o.w = f2bf(acc[jj][3]);
      *(us4*)(vt_ws + (size_t)(bh * 64 + jj * 16 + r) * 2048 + n0 + w * 16 + g * 4) = o;
    }
  } else {
    u16* dst = (s == 0) ? q_ws : k_ws;
    float sc = (s == 0) ? 0.125f : 1.0f;   // fold exact softmax scale into Q
    #pragma unroll
    for (int jj = 0; jj < 4; ++jj) {
      #pragma unroll
      for (int reg = 0; reg < 4; ++reg) {
        dst[(size_t)(bh * 2048 + n0 + w * 16 + 4 * g + reg) * 64 + jj * 16 + r] =
            f2bf(acc[jj][reg] * sc);
      }
    }
  }
}

// ---------------- kernel 2: fused scores + softmax + attn-write + PV ----------------
// block = 16 q-rows x 2048 cols; wave w owns cols [w*512, w*512+512)
// swapped mfma(K,Q): lane's 128 score regs all belong to q-row (lane&15)
__global__ __launch_bounds__(256, 2) void attn_kernel(const u16* __restrict__ q_ws,
    const u16* __restrict__ k_ws, const u16* __restrict__ vt_ws,
    float* __restrict__ attn, u16* __restrict__ o_ws) {
  __shared__ __align__(16) unsigned char smem[65536];   // 4 x 16KB per-wave P regions
  int qt = blockIdx.x;   // 0..127
  int bh = blockIdx.y;   // 0..47
  int w = threadIdx.x >> 6, lane = threadIdx.x & 63;
  int r = lane & 15, g = lane >> 4;

  const u16* qb = q_ws + (size_t)(bh * 2048 + qt * 16) * 64;
  short8 qf0 = *(const short8*)(qb + r * 64 + g * 8);
  short8 qf1 = *(const short8*)(qb + r * 64 + 32 + g * 8);

  f32x4 sacc[32];
  const u16* kb = k_ws + (size_t)(bh * 2048 + w * 512) * 64 + r * 64 + g * 8;
  #pragma unroll
  for (int t = 0; t < 32; ++t) {
    short8 kf0 = *(const short8*)(kb + (size_t)t * 1024);
    short8 kf1 = *(const short8*)(kb + (size_t)t * 1024 + 32);
    f32x4 a = (f32x4){0.f, 0.f, 0.f, 0.f};
    a = MFMA16(kf0, qf0, a);
    a = MFMA16(kf1, qf1, a);
    sacc[t] = a;
  }
  // ---- row max (lane owns one q-row) ----
  float m = -3.4e38f;
  #pragma unroll
  for (int t = 0; t < 32; ++t)
    m = fmaxf(m, fmaxf(fmaxf(sacc[t][0], sacc[t][1]), fmaxf(sacc[t][2], sacc[t][3])));
  m = fmaxf(m, __shfl_xor(m, 16));
  m = fmaxf(m, __shfl_xor(m, 32));
  float* red = (float*)smem;
  if (lane < 16) red[w * 16 + lane] = m;
  __syncthreads();
  m = fmaxf(fmaxf(red[r], red[16 + r]), fmaxf(red[32 + r], red[48 + r]));
  __syncthreads();
  // ---- exp + row sum ----
  float sum = 0.f;
  #pragma unroll
  for (int t = 0; t < 32; ++t) {
    #pragma unroll
    for (int e = 0; e < 4; ++e) {
      float p = __expf(sacc[t][e] - m);
      sacc[t][e] = p;
      sum += p;
    }
  }
  sum += __shfl_xor(sum, 16);
  sum += __shfl_xor(sum, 32);
  if (lane < 16) red[w * 16 + lane] = sum;
  __syncthreads();
  float lsum = (red[r] + red[16 + r]) + (red[32 + r] + red[48 + r]);
  __syncthreads();   // red reads done before wave0 overwrites with P
  float inv = 1.0f / lsum;

  // ---- write normalized attn to global + stage bf16 P to swizzled LDS ----
  unsigned char* pbase = smem + w * 16384;   // [16 rows][512 cols] bf16, XOR-swizzled
  float* arow = attn + ((size_t)bh * 2048 + qt * 16 + r) * 2048 + w * 512 + g * 4;
  #pragma unroll
  for (int t = 0; t < 32; ++t) {
    f32x4 p;
    p[0] = sacc[t][0] * inv; p[1] = sacc[t][1] * inv;
    p[2] = sacc[t][2] * inv; p[3] = sacc[t][3] * inv;
    *(f32x4*)(arow + t * 16) = p;
    us4 o; o.x = f2bf(p[0]); o.y = f2bf(p[1]); o.z = f2bf(p[2]); o.w = f2bf(p[3]);
    *(us4*)(pbase + ((r * 1024 + t * 32 + g * 8) ^ ((r & 7) << 4))) = o;
  }
  // ---- PV: O^T = Vt_chunk x P^T (wave-local LDS, no barrier needed) ----
  f32x4 oacc[4];
  #pragma unroll
  for (int dt = 0; dt < 4; ++dt) oacc[dt] = (f32x4){0.f, 0.f, 0.f, 0.f};
  const u16* vtb = vt_ws + (size_t)bh * 64 * 2048 + w * 512 + g * 8;
  #pragma unroll
  for (int cc = 0; cc < 16; ++cc) {
    short8 pf = *(const short8*)(pbase + ((r * 1024 + cc * 64 + g * 16) ^ ((r & 7) << 4)));
    #pragma unroll
    for (int dt = 0; dt < 4; ++dt) {
      short8 vf = *(const short8*)(vtb + (size_t)(dt * 16 + r) * 2048 + cc * 32);
      oacc[dt] = MFMA16(vf, pf, oacc[dt]);
    }
  }
  // ---- cross-wave O reduce (reuse own P region as fp32 [16][68]) ----
  float* ob = (float*)(smem + w * 16384);
  #pragma unroll
  for (int dt = 0; dt < 4; ++dt)
    *(f32x4*)(ob + r * 68 + dt * 16 + g * 4) = oacc[dt];
  __syncthreads();
  int tid = threadIdx.x;
  int rr = tid >> 4, d0 = (tid & 15) * 4;
  f32x4 v = (f32x4){0.f, 0.f, 0.f, 0.f};
  #pragma unroll
  for (int ww = 0; ww < 4; ++ww) {
    f32x4 part = *(const f32x4*)(smem + ww * 16384 + (rr * 68 + d0) * 4);
    v[0] += part[0]; v[1] += part[1]; v[2] += part[2]; v[3] += part[3];
  }
  int b = bh / 6, h = bh % 6;
  us4 o; o.x = f2bf(v[0]); o.y = f2bf(v[1]); o.z = f2bf(v[2]); o.w = f2bf(v[3]);
  *(us4*)(o_ws + (size_t)(b * 2048 + qt * 16 + rr) * 384 + h * 64 + d0) = o;
}

// ---------------- kernel 3: output projection + bias ----------------
__global__ __launch_bounds__(256) void proj_kernel(const u16* __restrict__ o_ws,
    const u16* __restrict__ wp_bf, const float* __restrict__ bias,
    float* __restrict__ out) {
  int jt = blockIdx.x;   // 0..5
  int mt = blockIdx.y;   // 0..255
  int w = threadIdx.x >> 6, lane = threadIdx.x & 63;
  int r = lane & 15, g = lane >> 4;
  int m0 = mt * 64 + w * 16;
  f32x4 acc[4];
  #pragma unroll
  for (int jj = 0; jj < 4; ++jj) acc[jj] = (f32x4){0.f, 0.f, 0.f, 0.f};
  const u16* arow = o_ws + (size_t)(m0 + r) * 384 + g * 8;
  const u16* wrow = wp_bf + (size_t)(jt * 64 + r) * 384 + g * 8;
  #pragma unroll
  for (int ks = 0; ks < 12; ++ks) {
    short8 af = *(const short8*)(arow + ks * 32);
    #pragma unroll
    for (int jj = 0; jj < 4; ++jj) {
      short8 bfr = *(const short8*)(wrow + (size_t)jj * 16 * 384 + ks * 32);
      acc[jj] = MFMA16(af, bfr, acc[jj]);
    }
  }
  #pragma unroll
  for (int jj = 0; jj < 4; ++jj) {
    float bj = bias[jt * 64 + jj * 16 + r];
    #pragma unroll
    for (int reg = 0; reg < 4; ++reg) {
      out[(size_t)(m0 + 4 * g + reg) * 384 + jt * 64 + jj * 16 + r] = acc[jj][reg] + bj;
    }
  }
}

extern "C" void kernel_launch(void* const* d_in, const int* in_sizes, int n_in,
                              void* d_out, int out_size, void* d_ws, size_t ws_size,
                              hipStream_t stream) {
  const float* x    = (const float*)d_in[0];
  const float* wq   = (const float*)d_in[1];
  const float* wp   = (const float*)d_in[2];
  const float* bias = (const float*)d_in[3];
  float* out  = (float*)d_out;
  float* attn = out + 6291456;           // tuple: out [8,2048,384] then attn [8,6,2048,2048]

  unsigned char* ws = (unsigned char*)d_ws;
  u16* x_bf  = (u16*)(ws);               // 12,582,912 B
  u16* wq_bf = (u16*)(ws + 12582912);    //    884,736 B
  u16* wp_bf = (u16*)(ws + 13467648);    //    294,912 B
  u16* q_ws  = (u16*)(ws + 13762560);    // 12,582,912 B  [bh][n][64], pre-scaled 1/8
  u16* k_ws  = (u16*)(ws + 26345472);    // 12,582,912 B  [bh][n][64]
  u16* vt_ws = (u16*)(ws + 38928384);    // 12,582,912 B  [bh][64][n]  (transposed)
  u16* o_ws  = (u16*)(ws + 51511296);    // 12,582,912 B  [b][n][384]
  // total ws use: 64,094,208 B

  cvt_kernel<<<2048, 256, 0, stream>>>(x, wq, wp, x_bf, wq_bf, wp_bf);
  qkv_kernel<<<dim3(18, 256), 256, 0, stream>>>(x_bf, wq_bf, q_ws, k_ws, vt_ws);
  attn_kernel<<<dim3(128, 48), 256, 0, stream>>>(q_ws, k_ws, vt_ws, attn, o_ws);
  proj_kernel<<<dim3(6, 256), 256, 0, stream>>>(o_ws, wp_bf, bias, out);
}